// Round 1
// baseline (513.308 us; speedup 1.0000x reference)
//
#include <hip/hip_runtime.h>
#include <hip/hip_bf16.h>
#include <math.h>

#define BATCH     256
#define DMODEL    2048
#define DSTATE    128
#define HEADDIM_  64
#define DINNER    4096
#define NHEADS_   64
#define CONVDIM   4352
#define DINPROJ   8512
#define EPS_      1e-5f

// ---------------- GEMM: C[M][N] = A[M][K] * B[N][K]^T (both K-contiguous) ----------------
template<int BM, int BN, int BK>
__global__ __launch_bounds__(256)
void gemm_tn(const float* __restrict__ A, const float* __restrict__ Bmat,
             float* __restrict__ C, int K, int N) {
    __shared__ float As[BK][BM + 4];
    __shared__ float Bs[BK][BN + 4];
    const int tid = threadIdx.x;
    const int bm0 = blockIdx.y * BM;
    const int bn0 = blockIdx.x * BN;
    const int r = tid >> 4;          // 0..15 -> output rows r*4..r*4+3
    const int c = tid & 15;          // 0..15 -> output cols c*4..c*4+3
    const int lm = tid >> 2;         // 0..63  (tile row for staging)
    const int kq = (tid & 3) * 4;    // k offset for staging (float4)
    float acc[4][4] = {};
    const float* Arow = A + (size_t)(bm0 + lm) * K + kq;
    const float* Brow = Bmat + (size_t)(bn0 + lm) * K + kq;

    for (int k0 = 0; k0 < K; k0 += BK) {
        float4 av = *(const float4*)(Arow + k0);
        float4 bv = *(const float4*)(Brow + k0);
        __syncthreads();
        As[kq + 0][lm] = av.x; As[kq + 1][lm] = av.y;
        As[kq + 2][lm] = av.z; As[kq + 3][lm] = av.w;
        Bs[kq + 0][lm] = bv.x; Bs[kq + 1][lm] = bv.y;
        Bs[kq + 2][lm] = bv.z; Bs[kq + 3][lm] = bv.w;
        __syncthreads();
        #pragma unroll
        for (int kk = 0; kk < BK; ++kk) {
            float4 a4 = *(const float4*)&As[kk][r * 4];
            float4 b4 = *(const float4*)&Bs[kk][c * 4];
            const float* ap = (const float*)&a4;
            const float* bp = (const float*)&b4;
            #pragma unroll
            for (int i = 0; i < 4; ++i)
                #pragma unroll
                for (int j = 0; j < 4; ++j)
                    acc[i][j] += ap[i] * bp[j];
        }
    }
    #pragma unroll
    for (int i = 0; i < 4; ++i) {
        float4 o = { acc[i][0], acc[i][1], acc[i][2], acc[i][3] };
        *(float4*)&C[(size_t)(bm0 + r * 4 + i) * N + bn0 + c * 4] = o;
    }
}

// ---------------- conv1d update + SiLU over CONV_DIM channels ----------------
__global__ __launch_bounds__(256)
void conv_silu(const float* __restrict__ zx, const float* __restrict__ conv_state,
               const float* __restrict__ conv_w, const float* __restrict__ conv_b,
               float* __restrict__ xbc) {
    int idx = blockIdx.x * 256 + threadIdx.x;     // b*CONVDIM + c
    int b = idx / CONVDIM, c = idx % CONVDIM;
    float4 cs = *(const float4*)&conv_state[(size_t)idx * 4];
    float4 w  = *(const float4*)&conv_w[c * 4];
    float xin = zx[(size_t)b * DINPROJ + DINNER + c];
    float v = cs.y * w.x + cs.z * w.y + cs.w * w.z + xin * w.w + conv_b[c];
    xbc[idx] = v / (1.f + expf(-v));
}

// ---------------- per-(b,h) scalars: dt, dA; per-b: B·C ----------------
__global__ __launch_bounds__(128)
void scalars_kernel(const float* __restrict__ zx, const float* __restrict__ xbc,
                    const float* __restrict__ dt_bias, const float* __restrict__ A_log,
                    float* __restrict__ dtv, float* __restrict__ dAv, float* __restrict__ BCv) {
    int b = blockIdx.x, t = threadIdx.x;          // 128 threads
    float prod = xbc[(size_t)b * CONVDIM + DINNER + t] *
                 xbc[(size_t)b * CONVDIM + DINNER + DSTATE + t];
    #pragma unroll
    for (int m = 1; m < 64; m <<= 1) prod += __shfl_xor(prod, m);
    __shared__ float wsum[2];
    if ((t & 63) == 0) wsum[t >> 6] = prod;
    __syncthreads();
    if (t == 0) BCv[b] = wsum[0] + wsum[1];
    if (t < NHEADS_) {
        float x = zx[(size_t)b * DINPROJ + DINNER + CONVDIM + t] + dt_bias[t];
        float dt = (x > 20.f) ? x : log1pf(expf(x));
        float dA = expf(dt * (-expf(A_log[t])));
        dtv[b * NHEADS_ + t] = dt;
        dAv[b * NHEADS_ + t] = dA;
    }
}

// ---------------- SSM: y[b,h,p] = dA*(ssm[b,h,p,:]·C[b]) + x*(dt*(B·C)+D[h]) ----------------
__global__ __launch_bounds__(256)
void ssm_kernel(const float* __restrict__ ssm, const float* __restrict__ xbc,
                const float* __restrict__ dtv, const float* __restrict__ dAv,
                const float* __restrict__ BCv, const float* __restrict__ Dp,
                float* __restrict__ y) {
    const int bh = blockIdx.x;
    const int b = bh >> 6, h = bh & 63;
    const int t = threadIdx.x;
    const float* S  = ssm + (size_t)bh * (HEADDIM_ * DSTATE);
    const float* Cp = xbc + (size_t)b * CONVDIM + DINNER + DSTATE;
    const float* xp = xbc + (size_t)b * CONVDIM + h * HEADDIM_;
    const float dA = dAv[bh];
    const float coef = dtv[bh] * BCv[b] + Dp[h];
    float4 c4 = *(const float4*)&Cp[(t & 31) * 4];
    #pragma unroll
    for (int it = 0; it < 8; ++it) {
        float4 s4 = *(const float4*)&S[it * 1024 + t * 4];   // fully coalesced
        float dot = s4.x * c4.x + s4.y * c4.y + s4.z * c4.z + s4.w * c4.w;
        #pragma unroll
        for (int m = 1; m < 32; m <<= 1) dot += __shfl_xor(dot, m);
        if ((t & 31) == 0) {
            int p = it * 8 + (t >> 5);
            y[(size_t)b * DINNER + h * HEADDIM_ + p] = dA * dot + xp[p] * coef;
        }
    }
}

// ---------------- gate with silu(z) + RMSNorm ----------------
__global__ __launch_bounds__(256)
void gate_norm(const float* __restrict__ y, const float* __restrict__ zx,
               const float* __restrict__ nw, float* __restrict__ yn) {
    const int b = blockIdx.x, t = threadIdx.x;
    float4 g[4];
    float ss = 0.f;
    #pragma unroll
    for (int it = 0; it < 4; ++it) {
        int i = it * 1024 + t * 4;
        float4 yv = *(const float4*)&y[(size_t)b * DINNER + i];
        float4 zv = *(const float4*)&zx[(size_t)b * DINPROJ + i];
        float4 gv;
        gv.x = yv.x * (zv.x / (1.f + expf(-zv.x)));
        gv.y = yv.y * (zv.y / (1.f + expf(-zv.y)));
        gv.z = yv.z * (zv.z / (1.f + expf(-zv.z)));
        gv.w = yv.w * (zv.w / (1.f + expf(-zv.w)));
        g[it] = gv;
        ss += gv.x * gv.x + gv.y * gv.y + gv.z * gv.z + gv.w * gv.w;
    }
    #pragma unroll
    for (int m = 1; m < 64; m <<= 1) ss += __shfl_xor(ss, m);
    __shared__ float wsum[4];
    if ((t & 63) == 0) wsum[t >> 6] = ss;
    __syncthreads();
    float tot = wsum[0] + wsum[1] + wsum[2] + wsum[3];
    float sc = rsqrtf(tot * (1.f / DINNER) + EPS_);
    #pragma unroll
    for (int it = 0; it < 4; ++it) {
        int i = it * 1024 + t * 4;
        float4 wv = *(const float4*)&nw[i];
        float4 gv = g[it];
        float4 o = { gv.x * sc * wv.x, gv.y * sc * wv.y, gv.z * sc * wv.z, gv.w * sc * wv.w };
        *(float4*)&yn[(size_t)b * DINNER + i] = o;
    }
}

extern "C" void kernel_launch(void* const* d_in, const int* in_sizes, int n_in,
                              void* d_out, int out_size, void* d_ws, size_t ws_size,
                              hipStream_t stream) {
    const float* hid        = (const float*)d_in[0];
    const float* conv_state = (const float*)d_in[1];
    const float* ssm        = (const float*)d_in[2];
    const float* W_in       = (const float*)d_in[3];
    const float* conv_w     = (const float*)d_in[4];
    const float* conv_b     = (const float*)d_in[5];
    const float* dt_bias    = (const float*)d_in[6];
    const float* A_log      = (const float*)d_in[7];
    const float* Dp         = (const float*)d_in[8];
    const float* norm_w     = (const float*)d_in[9];
    const float* W_out      = (const float*)d_in[10];
    float* out = (float*)d_out;

    float* ws   = (float*)d_ws;
    float* zx   = ws;                                  // 256*8512
    float* xbc  = zx  + (size_t)BATCH * DINPROJ;       // 256*4352
    float* y    = xbc + (size_t)BATCH * CONVDIM;       // 256*4096
    float* yn   = y   + (size_t)BATCH * DINNER;        // 256*4096
    float* dtv  = yn  + (size_t)BATCH * DINNER;        // 256*64
    float* dAv  = dtv + BATCH * NHEADS_;               // 256*64
    float* BCv  = dAv + BATCH * NHEADS_;               // 256

    // 1) zxbcdt = h @ W_in^T   (M=256, N=8512, K=2048)
    gemm_tn<64, 64, 16><<<dim3(DINPROJ / 64, BATCH / 64), 256, 0, stream>>>(
        hid, W_in, zx, DMODEL, DINPROJ);
    // 2) conv update + silu
    conv_silu<<<dim3(BATCH * CONVDIM / 256), 256, 0, stream>>>(
        zx, conv_state, conv_w, conv_b, xbc);
    // 3) dt/dA/(B·C)
    scalars_kernel<<<dim3(BATCH), 128, 0, stream>>>(
        zx, xbc, dt_bias, A_log, dtv, dAv, BCv);
    // 4) SSM contraction (reads 512 MiB ssm_state)
    ssm_kernel<<<dim3(BATCH * NHEADS_), 256, 0, stream>>>(
        ssm, xbc, dtv, dAv, BCv, Dp, y);
    // 5) gate + RMSNorm
    gate_norm<<<dim3(BATCH), 256, 0, stream>>>(y, zx, norm_w, yn);
    // 6) out = yn @ W_out^T   (M=256, N=2048, K=4096)
    gemm_tn<64, 64, 16><<<dim3(DMODEL / 64, BATCH / 64), 256, 0, stream>>>(
        yn, W_out, out, DINNER, DMODEL);
}

// Round 2
// 228.902 us; speedup vs baseline: 2.2425x; 2.2425x over previous
//
#include <hip/hip_runtime.h>
#include <hip/hip_bf16.h>
#include <math.h>

#define BATCH     256
#define DMODEL    2048
#define DSTATE    128
#define HEADDIM_  64
#define DINNER    4096
#define NHEADS_   64
#define CONVDIM   4352
#define DINPROJ   8512
#define EPS_      1e-5f

typedef __attribute__((ext_vector_type(8))) short short8;
typedef __attribute__((ext_vector_type(4))) float f32x4;

__device__ __forceinline__ short bfbits(float f) {
    __hip_bfloat16 h = __float2bfloat16(f);
    return *reinterpret_cast<short*>(&h);
}
__device__ __forceinline__ short8 cvt8(float4 a, float4 b) {
    short8 r;
    r[0] = bfbits(a.x); r[1] = bfbits(a.y); r[2] = bfbits(a.z); r[3] = bfbits(a.w);
    r[4] = bfbits(b.x); r[5] = bfbits(b.y); r[6] = bfbits(b.z); r[7] = bfbits(b.w);
    return r;
}
// XOR-swizzled byte offset into a [rows][32] bf16 tile (64B rows); spreads
// stride-64B fragment reads across banks (2-way = free per m136).
__device__ __forceinline__ int swz(int row, int cb) {
    return row * 64 + (cb ^ (((row >> 1) & 3) << 4));
}

// ---------------- bf16 MFMA GEMM: C[256][N] = A[256][K]*W[N][K]^T ----------------
// BM=256 (full M, W read once), BN=64, BK=32, 512 thr / 8 waves (4 row x 2 col),
// each wave 64x32 out = 4x2 frags of 16x16, reg-staged f32->bf16 conversion.
// Split-K via gridDim.y: block y=s computes k-range [s*kc, (s+1)*kc) into C + s*256*ldc.
__global__ __launch_bounds__(512, 1)
void gemm_mfma(const float* __restrict__ A, const float* __restrict__ W,
               float* __restrict__ C, int lda, int ldb, int ldc, int kc) {
    const int bn0 = blockIdx.x * 64;
    const int k0  = blockIdx.y * kc;
    C += (size_t)blockIdx.y * 256 * ldc;
    const int t = threadIdx.x;
    const int lane = t & 63;
    const int w = t >> 6;
    const int wr = w >> 1, wc = w & 1;

    __shared__ __align__(16) char lds[(256 * 32 + 64 * 32) * 2];  // 20 KB: A then B
    char* ldsA = lds;
    char* ldsB = lds + 256 * 32 * 2;

    // staging map: thread -> (row = t>>2, 16B slot = t&3); 8 consecutive f32 per thread
    const int srow = t >> 2;          // 0..127
    const int skc  = (t & 3) * 8;     // element k offset
    const int scb  = (t & 3) * 16;    // byte col
    const float* Ap0 = A + (size_t)srow * lda + k0 + skc;
    const float* Ap1 = A + (size_t)(srow + 128) * lda + k0 + skc;
    const float* Wp  = W + (size_t)(bn0 + srow) * ldb + k0 + skc;  // deref only if t<256
    const int aoff0 = swz(srow, scb);
    const int aoff1 = swz(srow + 128, scb);
    const int boff  = swz(srow, scb);

    // fragment read offsets (A/B frag: lane holds 8 k-contig bf16 at row lane&15, kgrp lane>>4)
    const int fr = lane & 15, fg = lane >> 4;
    int aro[4], bro[2];
    #pragma unroll
    for (int m = 0; m < 4; ++m) aro[m] = swz(wr * 64 + m * 16 + fr, fg * 16);
    #pragma unroll
    for (int n = 0; n < 2; ++n) bro[n] = swz(wc * 32 + n * 16 + fr, fg * 16);

    f32x4 acc[4][2] = {};
    float4 ra0a = {}, ra0b = {}, ra1a = {}, ra1b = {}, rb0 = {}, rb1 = {};

    // preload tile 0
    ra0a = *(const float4*)(Ap0);     ra0b = *(const float4*)(Ap0 + 4);
    ra1a = *(const float4*)(Ap1);     ra1b = *(const float4*)(Ap1 + 4);
    if (t < 256) { rb0 = *(const float4*)(Wp); rb1 = *(const float4*)(Wp + 4); }

    const int nT = kc >> 5;
    for (int kt = 0; kt < nT; ++kt) {
        __syncthreads();
        *(short8*)(ldsA + aoff0) = cvt8(ra0a, ra0b);
        *(short8*)(ldsA + aoff1) = cvt8(ra1a, ra1b);
        if (t < 256) *(short8*)(ldsB + boff) = cvt8(rb0, rb1);
        __syncthreads();
        if (kt + 1 < nT) {   // issue next-tile loads; stay in flight across MFMA
            const int ko = (kt + 1) << 5;
            ra0a = *(const float4*)(Ap0 + ko); ra0b = *(const float4*)(Ap0 + ko + 4);
            ra1a = *(const float4*)(Ap1 + ko); ra1b = *(const float4*)(Ap1 + ko + 4);
            if (t < 256) { rb0 = *(const float4*)(Wp + ko); rb1 = *(const float4*)(Wp + ko + 4); }
        }
        short8 af[4], bf[2];
        #pragma unroll
        for (int m = 0; m < 4; ++m) af[m] = *(short8*)(ldsA + aro[m]);
        #pragma unroll
        for (int n = 0; n < 2; ++n) bf[n] = *(short8*)(ldsB + bro[n]);
        #pragma unroll
        for (int m = 0; m < 4; ++m)
            #pragma unroll
            for (int n = 0; n < 2; ++n)
                acc[m][n] = __builtin_amdgcn_mfma_f32_16x16x32_bf16(af[m], bf[n], acc[m][n], 0, 0, 0);
    }
    // epilogue: C/D layout col=lane&15, row=(lane>>4)*4+j  [m89-verified]
    #pragma unroll
    for (int m = 0; m < 4; ++m)
        #pragma unroll
        for (int n = 0; n < 2; ++n) {
            const int row = wr * 64 + m * 16 + fg * 4;
            const int col = bn0 + wc * 32 + n * 16 + fr;
            #pragma unroll
            for (int j = 0; j < 4; ++j)
                C[(size_t)(row + j) * ldc + col] = acc[m][n][j];
        }
}

// sum 8 split-K partials
__global__ __launch_bounds__(256)
void reduce8(const float* __restrict__ part, float* __restrict__ out) {
    const int i = (blockIdx.x * 256 + threadIdx.x) * 4;
    float4 s = *(const float4*)(part + i);
    #pragma unroll
    for (int k = 1; k < 8; ++k) {
        float4 p = *(const float4*)(part + (size_t)k * BATCH * DMODEL + i);
        s.x += p.x; s.y += p.y; s.z += p.z; s.w += p.w;
    }
    *(float4*)(out + i) = s;
}

// ---------------- conv1d update + SiLU over CONV_DIM channels ----------------
__global__ __launch_bounds__(256)
void conv_silu(const float* __restrict__ zx, const float* __restrict__ conv_state,
               const float* __restrict__ conv_w, const float* __restrict__ conv_b,
               float* __restrict__ xbc) {
    int idx = blockIdx.x * 256 + threadIdx.x;
    int b = idx / CONVDIM, c = idx % CONVDIM;
    float4 cs = *(const float4*)&conv_state[(size_t)idx * 4];
    float4 w  = *(const float4*)&conv_w[c * 4];
    float xin = zx[(size_t)b * DINPROJ + DINNER + c];
    float v = cs.y * w.x + cs.z * w.y + cs.w * w.z + xin * w.w + conv_b[c];
    xbc[idx] = v / (1.f + expf(-v));
}

// ---------------- per-(b,h) scalars: dt, dA; per-b: B·C ----------------
__global__ __launch_bounds__(128)
void scalars_kernel(const float* __restrict__ zx, const float* __restrict__ xbc,
                    const float* __restrict__ dt_bias, const float* __restrict__ A_log,
                    float* __restrict__ dtv, float* __restrict__ dAv, float* __restrict__ BCv) {
    int b = blockIdx.x, t = threadIdx.x;
    float prod = xbc[(size_t)b * CONVDIM + DINNER + t] *
                 xbc[(size_t)b * CONVDIM + DINNER + DSTATE + t];
    #pragma unroll
    for (int m = 1; m < 64; m <<= 1) prod += __shfl_xor(prod, m);
    __shared__ float wsum[2];
    if ((t & 63) == 0) wsum[t >> 6] = prod;
    __syncthreads();
    if (t == 0) BCv[b] = wsum[0] + wsum[1];
    if (t < NHEADS_) {
        float x = zx[(size_t)b * DINPROJ + DINNER + CONVDIM + t] + dt_bias[t];
        float dt = (x > 20.f) ? x : log1pf(expf(x));
        float dA = expf(dt * (-expf(A_log[t])));
        dtv[b * NHEADS_ + t] = dt;
        dAv[b * NHEADS_ + t] = dA;
    }
}

// ---------------- SSM: y[b,h,p] = dA*(ssm[b,h,p,:]·C[b]) + x*(dt*(B·C)+D[h]) ----------------
__global__ __launch_bounds__(256)
void ssm_kernel(const float* __restrict__ ssm, const float* __restrict__ xbc,
                const float* __restrict__ dtv, const float* __restrict__ dAv,
                const float* __restrict__ BCv, const float* __restrict__ Dp,
                float* __restrict__ y) {
    const int bh = blockIdx.x;
    const int b = bh >> 6, h = bh & 63;
    const int t = threadIdx.x;
    const float* S  = ssm + (size_t)bh * (HEADDIM_ * DSTATE);
    const float* Cp = xbc + (size_t)b * CONVDIM + DINNER + DSTATE;
    const float* xp = xbc + (size_t)b * CONVDIM + h * HEADDIM_;
    const float dA = dAv[bh];
    const float coef = dtv[bh] * BCv[b] + Dp[h];
    float4 c4 = *(const float4*)&Cp[(t & 31) * 4];
    #pragma unroll
    for (int it = 0; it < 8; ++it) {
        float4 s4 = *(const float4*)&S[it * 1024 + t * 4];
        float dot = s4.x * c4.x + s4.y * c4.y + s4.z * c4.z + s4.w * c4.w;
        #pragma unroll
        for (int m = 1; m < 32; m <<= 1) dot += __shfl_xor(dot, m);
        if ((t & 31) == 0) {
            int p = it * 8 + (t >> 5);
            y[(size_t)b * DINNER + h * HEADDIM_ + p] = dA * dot + xp[p] * coef;
        }
    }
}

// ---------------- gate with silu(z) + RMSNorm ----------------
__global__ __launch_bounds__(256)
void gate_norm(const float* __restrict__ y, const float* __restrict__ zx,
               const float* __restrict__ nw, float* __restrict__ yn) {
    const int b = blockIdx.x, t = threadIdx.x;
    float4 g[4];
    float ss = 0.f;
    #pragma unroll
    for (int it = 0; it < 4; ++it) {
        int i = it * 1024 + t * 4;
        float4 yv = *(const float4*)&y[(size_t)b * DINNER + i];
        float4 zv = *(const float4*)&zx[(size_t)b * DINPROJ + i];
        float4 gv;
        gv.x = yv.x * (zv.x / (1.f + expf(-zv.x)));
        gv.y = yv.y * (zv.y / (1.f + expf(-zv.y)));
        gv.z = yv.z * (zv.z / (1.f + expf(-zv.z)));
        gv.w = yv.w * (zv.w / (1.f + expf(-zv.w)));
        g[it] = gv;
        ss += gv.x * gv.x + gv.y * gv.y + gv.z * gv.z + gv.w * gv.w;
    }
    #pragma unroll
    for (int m = 1; m < 64; m <<= 1) ss += __shfl_xor(ss, m);
    __shared__ float wsum[4];
    if ((t & 63) == 0) wsum[t >> 6] = ss;
    __syncthreads();
    float tot = wsum[0] + wsum[1] + wsum[2] + wsum[3];
    float sc = rsqrtf(tot * (1.f / DINNER) + EPS_);
    #pragma unroll
    for (int it = 0; it < 4; ++it) {
        int i = it * 1024 + t * 4;
        float4 wv = *(const float4*)&nw[i];
        float4 gv = g[it];
        float4 o = { gv.x * sc * wv.x, gv.y * sc * wv.y, gv.z * sc * wv.z, gv.w * sc * wv.w };
        *(float4*)&yn[(size_t)b * DINNER + i] = o;
    }
}

extern "C" void kernel_launch(void* const* d_in, const int* in_sizes, int n_in,
                              void* d_out, int out_size, void* d_ws, size_t ws_size,
                              hipStream_t stream) {
    const float* hid        = (const float*)d_in[0];
    const float* conv_state = (const float*)d_in[1];
    const float* ssm        = (const float*)d_in[2];
    const float* W_in       = (const float*)d_in[3];
    const float* conv_w     = (const float*)d_in[4];
    const float* conv_b     = (const float*)d_in[5];
    const float* dt_bias    = (const float*)d_in[6];
    const float* A_log      = (const float*)d_in[7];
    const float* Dp         = (const float*)d_in[8];
    const float* norm_w     = (const float*)d_in[9];
    const float* W_out      = (const float*)d_in[10];
    float* out = (float*)d_out;

    float* ws   = (float*)d_ws;
    float* zx   = ws;                                  // 256*8512
    float* xbc  = zx  + (size_t)BATCH * DINPROJ;       // 256*4352
    float* y    = xbc + (size_t)BATCH * CONVDIM;       // 256*4096
    float* yn   = y   + (size_t)BATCH * DINNER;        // 256*4096
    float* part = yn  + (size_t)BATCH * DINNER;        // 8*256*2048
    float* dtv  = part + (size_t)8 * BATCH * DMODEL;   // 256*64
    float* dAv  = dtv + BATCH * NHEADS_;               // 256*64
    float* BCv  = dAv + BATCH * NHEADS_;               // 256

    // 1) zxbcdt = h @ W_in^T   (M=256, N=8512, K=2048); W_in read once
    gemm_mfma<<<dim3(DINPROJ / 64, 1), 512, 0, stream>>>(
        hid, W_in, zx, DMODEL, DMODEL, DINPROJ, DMODEL);
    // 2) conv update + silu
    conv_silu<<<dim3(BATCH * CONVDIM / 256), 256, 0, stream>>>(
        zx, conv_state, conv_w, conv_b, xbc);
    // 3) dt/dA/(B·C)
    scalars_kernel<<<dim3(BATCH), 128, 0, stream>>>(
        zx, xbc, dt_bias, A_log, dtv, dAv, BCv);
    // 4) SSM contraction (reads 512 MiB ssm_state)
    ssm_kernel<<<dim3(BATCH * NHEADS_), 256, 0, stream>>>(
        ssm, xbc, dtv, dAv, BCv, Dp, y);
    // 5) gate + RMSNorm
    gate_norm<<<dim3(BATCH), 256, 0, stream>>>(y, zx, norm_w, yn);
    // 6) out = yn @ W_out^T   (M=256, N=2048, K=4096), split-K x8 + reduce
    gemm_mfma<<<dim3(DMODEL / 64, 8), 512, 0, stream>>>(
        yn, W_out, part, DINNER, DINNER, DMODEL, DINNER / 8);
    reduce8<<<dim3(BATCH * DMODEL / 1024), 256, 0, stream>>>(part, out);
}

// Round 3
// 196.151 us; speedup vs baseline: 2.6169x; 1.1670x over previous
//
#include <hip/hip_runtime.h>
#include <hip/hip_bf16.h>
#include <math.h>

#define BATCH     256
#define DMODEL    2048
#define DSTATE    128
#define HEADDIM_  64
#define DINNER    4096
#define NHEADS_   64
#define CONVDIM   4352
#define DINPROJ   8512
#define EPS_      1e-5f

typedef __attribute__((ext_vector_type(8))) short short8;
typedef __attribute__((ext_vector_type(4))) float f32x4;

__device__ __forceinline__ short bfbits(float f) {
    __hip_bfloat16 h = __float2bfloat16(f);
    return *reinterpret_cast<short*>(&h);
}
__device__ __forceinline__ short8 cvt8(float4 a, float4 b) {
    short8 r;
    r[0] = bfbits(a.x); r[1] = bfbits(a.y); r[2] = bfbits(a.z); r[3] = bfbits(a.w);
    r[4] = bfbits(b.x); r[5] = bfbits(b.y); r[6] = bfbits(b.z); r[7] = bfbits(b.w);
    return r;
}
// XOR-swizzle for [rows][128B] bf16 LDS tiles: without it, stride-128B column
// reads are a 16-way bank conflict (G4). bits 4-6 of col ^= row&7.
__device__ __forceinline__ int swz(int row, int cb) {
    return row * 128 + (cb ^ ((row & 7) << 4));
}

// ---------------- bf16 MFMA GEMM: C[M][N] = A[M][K]*W[N][K]^T ----------------
// BM=128, BN=64, BK=64. 256 thr = 4 waves (2 wr x 2 wc), wave tile 64x32,
// 16 MFMA per K-step. Double-buffered LDS (2x24KB), ONE barrier per K-step.
// grid = (N/64, M/128, ksplit); block z writes partial to C + z*256*ldc.
__global__ __launch_bounds__(256, 3)
void gemm_mfma(const float* __restrict__ A, const float* __restrict__ W,
               float* __restrict__ C, int lda, int ldb, int ldc, int kc) {
    const int bn0 = blockIdx.x * 64;
    const int bm0 = blockIdx.y * 128;
    const int k0  = blockIdx.z * kc;
    C += (size_t)blockIdx.z * 256 * ldc;
    const int t = threadIdx.x;
    const int lane = t & 63;
    const int w = t >> 6;
    const int wr = w >> 1, wc = w & 1;
    const int fr = lane & 15, fg = lane >> 4;

    __shared__ __align__(16) char lds[2][24 * 1024];   // per buf: A 16K, B 8K

    // staging: slot s covers LDS row s>>3, 16B-slot s&7 (<- 32B of f32 source)
    const float* ap[4]; int ao[4];
    #pragma unroll
    for (int i = 0; i < 4; ++i) {
        int s = t + 256 * i, r = s >> 3, sl = s & 7;
        ap[i] = A + (size_t)(bm0 + r) * lda + k0 + sl * 8;
        ao[i] = swz(r, sl * 16);
    }
    const float* bp[2]; int bo[2];
    #pragma unroll
    for (int i = 0; i < 2; ++i) {
        int s = t + 256 * i, r = s >> 3, sl = s & 7;
        bp[i] = W + (size_t)(bn0 + r) * ldb + k0 + sl * 8;
        bo[i] = 16 * 1024 + swz(r, sl * 16);
    }
    // fragment read offsets (ks=0; ks=1 is ^64 since swizzle keeps bit6 XOR-clean)
    int aro[4], bro[2];
    #pragma unroll
    for (int m = 0; m < 4; ++m) aro[m] = swz(wr * 64 + m * 16 + fr, fg * 16);
    #pragma unroll
    for (int n = 0; n < 2; ++n) bro[n] = 16 * 1024 + swz(wc * 32 + n * 16 + fr, fg * 16);

    f32x4 acc[4][2] = {};
    float4 ra[4][2], rb[2][2];

    #define LOADT(kt) { int ko = (kt) << 6; \
        _Pragma("unroll") for (int i = 0; i < 4; ++i) { \
            ra[i][0] = *(const float4*)(ap[i] + ko); ra[i][1] = *(const float4*)(ap[i] + ko + 4); } \
        _Pragma("unroll") for (int i = 0; i < 2; ++i) { \
            rb[i][0] = *(const float4*)(bp[i] + ko); rb[i][1] = *(const float4*)(bp[i] + ko + 4); } }
    #define STAGET(buf) { \
        _Pragma("unroll") for (int i = 0; i < 4; ++i) *(short8*)(lds[buf] + ao[i]) = cvt8(ra[i][0], ra[i][1]); \
        _Pragma("unroll") for (int i = 0; i < 2; ++i) *(short8*)(lds[buf] + bo[i]) = cvt8(rb[i][0], rb[i][1]); }

    LOADT(0);
    STAGET(0);
    int cur = 0;
    const int nT = kc >> 6;
    for (int kt = 0; kt < nT; ++kt) {
        if (kt + 1 < nT) LOADT(kt + 1);
        __syncthreads();                        // buf[cur] ready; prior reads drained
        #pragma unroll
        for (int ks = 0; ks < 2; ++ks) {
            short8 af[4], bf[2];
            #pragma unroll
            for (int m = 0; m < 4; ++m) af[m] = *(short8*)(lds[cur] + (aro[m] ^ (ks << 6)));
            #pragma unroll
            for (int n = 0; n < 2; ++n) bf[n] = *(short8*)(lds[cur] + (bro[n] ^ (ks << 6)));
            #pragma unroll
            for (int m = 0; m < 4; ++m)
                #pragma unroll
                for (int n = 0; n < 2; ++n)
                    acc[m][n] = __builtin_amdgcn_mfma_f32_16x16x32_bf16(af[m], bf[n], acc[m][n], 0, 0, 0);
        }
        if (kt + 1 < nT) STAGET(cur ^ 1);
        cur ^= 1;
    }
    #pragma unroll
    for (int m = 0; m < 4; ++m)
        #pragma unroll
        for (int n = 0; n < 2; ++n) {
            const int row = bm0 + wr * 64 + m * 16 + fg * 4;
            const int col = bn0 + wc * 32 + n * 16 + fr;
            #pragma unroll
            for (int j = 0; j < 4; ++j)
                C[(size_t)(row + j) * ldc + col] = acc[m][n][j];
        }
    #undef LOADT
    #undef STAGET
}

// sum 4 split-K partials (gemm2)
__global__ __launch_bounds__(256)
void reduce4(const float* __restrict__ part, float* __restrict__ out) {
    const int i = (blockIdx.x * 256 + threadIdx.x) * 4;
    float4 s = *(const float4*)(part + i);
    #pragma unroll
    for (int k = 1; k < 4; ++k) {
        float4 p = *(const float4*)(part + (size_t)k * BATCH * DMODEL + i);
        s.x += p.x; s.y += p.y; s.z += p.z; s.w += p.w;
    }
    *(float4*)(out + i) = s;
}

// ---------------- fused conv1d+SiLU + per-(b,h) scalars ----------------
__global__ __launch_bounds__(256)
void conv_scalars(const float* __restrict__ zx, const float* __restrict__ conv_state,
                  const float* __restrict__ conv_w, const float* __restrict__ conv_b,
                  const float* __restrict__ dt_bias, const float* __restrict__ A_log,
                  float* __restrict__ xbc, float* __restrict__ dtv,
                  float* __restrict__ dAv, float* __restrict__ BCv) {
    const int b = blockIdx.x, t = threadIdx.x;
    __shared__ float sBC[256];
    __shared__ float ws2[2];
    #pragma unroll
    for (int it = 0; it < 17; ++it) {
        int c = it * 256 + t;
        float4 cs = *(const float4*)&conv_state[((size_t)b * CONVDIM + c) * 4];
        float4 w4 = *(const float4*)&conv_w[c * 4];
        float xin = zx[(size_t)b * DINPROJ + DINNER + c];
        float v = cs.y * w4.x + cs.z * w4.y + cs.w * w4.z + xin * w4.w + conv_b[c];
        float sv = v / (1.f + expf(-v));
        xbc[(size_t)b * CONVDIM + c] = sv;
        if (c >= DINNER) sBC[c - DINNER] = sv;
    }
    __syncthreads();
    if (t < 128) {
        float prod = sBC[t] * sBC[t + 128];
        #pragma unroll
        for (int m = 1; m < 64; m <<= 1) prod += __shfl_xor(prod, m);
        if ((t & 63) == 0) ws2[t >> 6] = prod;
    }
    __syncthreads();
    if (t == 0) BCv[b] = ws2[0] + ws2[1];
    if (t < NHEADS_) {
        float x = zx[(size_t)b * DINPROJ + DINNER + CONVDIM + t] + dt_bias[t];
        float dt = (x > 20.f) ? x : log1pf(expf(x));
        float dA = expf(dt * (-expf(A_log[t])));
        dtv[b * NHEADS_ + t] = dt;
        dAv[b * NHEADS_ + t] = dA;
    }
}

// ---------------- SSM: y[b,h,p] = dA*(ssm[b,h,p,:]·C[b]) + x*(dt*(B·C)+D[h]) ----------------
__global__ __launch_bounds__(256)
void ssm_kernel(const float* __restrict__ ssm, const float* __restrict__ xbc,
                const float* __restrict__ dtv, const float* __restrict__ dAv,
                const float* __restrict__ BCv, const float* __restrict__ Dp,
                float* __restrict__ y) {
    const int bh = blockIdx.x;
    const int b = bh >> 6, h = bh & 63;
    const int t = threadIdx.x;
    const float* S  = ssm + (size_t)bh * (HEADDIM_ * DSTATE);
    const float* Cp = xbc + (size_t)b * CONVDIM + DINNER + DSTATE;
    const float* xp = xbc + (size_t)b * CONVDIM + h * HEADDIM_;
    const float dA = dAv[bh];
    const float coef = dtv[bh] * BCv[b] + Dp[h];
    float4 c4 = *(const float4*)&Cp[(t & 31) * 4];
    #pragma unroll
    for (int it = 0; it < 8; ++it) {
        float4 s4 = *(const float4*)&S[it * 1024 + t * 4];
        float dot = s4.x * c4.x + s4.y * c4.y + s4.z * c4.z + s4.w * c4.w;
        #pragma unroll
        for (int m = 1; m < 32; m <<= 1) dot += __shfl_xor(dot, m);
        if ((t & 31) == 0) {
            int p = it * 8 + (t >> 5);
            y[(size_t)b * DINNER + h * HEADDIM_ + p] = dA * dot + xp[p] * coef;
        }
    }
}

// ---------------- gate with silu(z) + RMSNorm ----------------
__global__ __launch_bounds__(256)
void gate_norm(const float* __restrict__ y, const float* __restrict__ zx,
               const float* __restrict__ nw, float* __restrict__ yn) {
    const int b = blockIdx.x, t = threadIdx.x;
    float4 g[4];
    float ss = 0.f;
    #pragma unroll
    for (int it = 0; it < 4; ++it) {
        int i = it * 1024 + t * 4;
        float4 yv = *(const float4*)&y[(size_t)b * DINNER + i];
        float4 zv = *(const float4*)&zx[(size_t)b * DINPROJ + i];
        float4 gv;
        gv.x = yv.x * (zv.x / (1.f + expf(-zv.x)));
        gv.y = yv.y * (zv.y / (1.f + expf(-zv.y)));
        gv.z = yv.z * (zv.z / (1.f + expf(-zv.z)));
        gv.w = yv.w * (zv.w / (1.f + expf(-zv.w)));
        g[it] = gv;
        ss += gv.x * gv.x + gv.y * gv.y + gv.z * gv.z + gv.w * gv.w;
    }
    #pragma unroll
    for (int m = 1; m < 64; m <<= 1) ss += __shfl_xor(ss, m);
    __shared__ float wsum[4];
    if ((t & 63) == 0) wsum[t >> 6] = ss;
    __syncthreads();
    float tot = wsum[0] + wsum[1] + wsum[2] + wsum[3];
    float sc = rsqrtf(tot * (1.f / DINNER) + EPS_);
    #pragma unroll
    for (int it = 0; it < 4; ++it) {
        int i = it * 1024 + t * 4;
        float4 wv = *(const float4*)&nw[i];
        float4 gv = g[it];
        float4 o = { gv.x * sc * wv.x, gv.y * sc * wv.y, gv.z * sc * wv.z, gv.w * sc * wv.w };
        *(float4*)&yn[(size_t)b * DINNER + i] = o;
    }
}

extern "C" void kernel_launch(void* const* d_in, const int* in_sizes, int n_in,
                              void* d_out, int out_size, void* d_ws, size_t ws_size,
                              hipStream_t stream) {
    const float* hid        = (const float*)d_in[0];
    const float* conv_state = (const float*)d_in[1];
    const float* ssm        = (const float*)d_in[2];
    const float* W_in       = (const float*)d_in[3];
    const float* conv_w     = (const float*)d_in[4];
    const float* conv_b     = (const float*)d_in[5];
    const float* dt_bias    = (const float*)d_in[6];
    const float* A_log      = (const float*)d_in[7];
    const float* Dp         = (const float*)d_in[8];
    const float* norm_w     = (const float*)d_in[9];
    const float* W_out      = (const float*)d_in[10];
    float* out = (float*)d_out;

    float* ws   = (float*)d_ws;
    float* zx   = ws;                                  // 256*8512
    float* xbc  = zx  + (size_t)BATCH * DINPROJ;       // 256*4352
    float* y    = xbc + (size_t)BATCH * CONVDIM;       // 256*4096
    float* yn   = y   + (size_t)BATCH * DINNER;        // 256*4096
    float* part = yn  + (size_t)BATCH * DINNER;        // 4*256*2048
    float* dtv  = part + (size_t)4 * BATCH * DMODEL;   // 256*64
    float* dAv  = dtv + BATCH * NHEADS_;               // 256*64
    float* BCv  = dAv + BATCH * NHEADS_;               // 256

    // 1) zxbcdt = h @ W_in^T  (M=256,N=8512,K=2048): 266 blocks
    gemm_mfma<<<dim3(DINPROJ / 64, 2, 1), 256, 0, stream>>>(
        hid, W_in, zx, DMODEL, DMODEL, DINPROJ, DMODEL);
    // 2) conv update + silu + dt/dA/(B·C)
    conv_scalars<<<dim3(BATCH), 256, 0, stream>>>(
        zx, conv_state, conv_w, conv_b, dt_bias, A_log, xbc, dtv, dAv, BCv);
    // 3) SSM contraction (512 MiB ssm_state read)
    ssm_kernel<<<dim3(BATCH * NHEADS_), 256, 0, stream>>>(
        ssm, xbc, dtv, dAv, BCv, Dp, y);
    // 4) gate + RMSNorm
    gate_norm<<<dim3(BATCH), 256, 0, stream>>>(y, zx, norm_w, yn);
    // 5) out = yn @ W_out^T  (M=256,N=2048,K=4096): split-K x4 -> 256 blocks
    gemm_mfma<<<dim3(DMODEL / 64, 2, 4), 256, 0, stream>>>(
        yn, W_out, part, DINNER, DINNER, DMODEL, DINNER / 4);
    reduce4<<<dim3(BATCH * DMODEL / 1024), 256, 0, stream>>>(part, out);
}